// Round 2
// baseline (1401.838 us; speedup 1.0000x reference)
//
#include <hip/hip_runtime.h>
#include <math.h>

typedef short bf16x8 __attribute__((ext_vector_type(8)));
typedef float f32x4 __attribute__((ext_vector_type(4)));

__device__ __forceinline__ ushort f2bf(float f) {
    unsigned u = __float_as_uint(f);
    u = u + 0x7FFFu + ((u >> 16) & 1u);
    return (ushort)(u >> 16);
}
__device__ __forceinline__ float bf2f(ushort h) {
    return __uint_as_float(((unsigned)h) << 16);
}

#define LSTRIDE 40   // LDS row stride in bf16 elements (32 data + 8 pad, 80B rows)

// ---------------------------------------------------------------------------
// Stage 0: transpose embed[8150,300] -> Et[320][8192] bf16 hi/lo (pad = 0).
// ---------------------------------------------------------------------------
__global__ __launch_bounds__(256) void trans_kernel(
    const float* __restrict__ embed, ushort* __restrict__ Et_hi,
    ushort* __restrict__ Et_lo) {
    __shared__ float tile[64][65];
    int k0 = blockIdx.x * 64;
    int n0 = blockIdx.y * 64;
    int tid = threadIdx.x;
#pragma unroll
    for (int i = 0; i < 16; i++) {
        int idx = tid + i * 256;
        int r = idx >> 6, c = idx & 63;
        int gk = k0 + r, gn = n0 + c;
        float v = (gk < 8150 && gn < 300) ? embed[(size_t)gk * 300 + gn] : 0.f;
        tile[r][c] = v;
    }
    __syncthreads();
#pragma unroll
    for (int i = 0; i < 16; i++) {
        int idx = tid + i * 256;
        int n = idx >> 6, k = idx & 63;
        float v = tile[k][n];
        ushort h = f2bf(v);
        Et_hi[(size_t)(n0 + n) * 8192 + k0 + k] = h;
        Et_lo[(size_t)(n0 + n) * 8192 + k0 + k] = f2bf(v - bf2f(h));
    }
}

// ---------------------------------------------------------------------------
// Stage 1 (dominant GEMM): Eo[5888][320] += X[5888][8150] @ embed (via Et).
// T14 async-STAGE pipeline: issue t+1 global loads -> regs BEFORE MFMA of t;
// after post-MFMA barrier, vmcnt-wait (at use), cvt, ds_write, barrier.
// Raw s_barrier + asm lgkmcnt so in-flight vmem stays outstanding across
// barriers. Single LDS buffer (write-after-read ordered by barrier 1).
// grid (46 m-blocks of 128, 2 n-cols of 160, 16 k-chunks of 512), 512 thr.
// ---------------------------------------------------------------------------
__global__ __launch_bounds__(512, 4) void e_kernel(
    const float* __restrict__ X, const ushort* __restrict__ Et_hi,
    const ushort* __restrict__ Et_lo, float* __restrict__ Eo) {
    __shared__ ushort Ah[128 * LSTRIDE], Al[128 * LSTRIDE];
    __shared__ ushort Bh[160 * LSTRIDE], Bl[160 * LSTRIDE];
    int bm = blockIdx.x * 128;
    int bn = blockIdx.y * 160;
    int kc = blockIdx.z * 512;
    int tid = threadIdx.x;
    int lane = tid & 63, w = tid >> 6;
    int quad = lane >> 4, l16 = lane & 15;
    int wm = (w & 3) * 32, wn = (w >> 2) * 80;

    f32x4 acc[2][5];
#pragma unroll
    for (int a = 0; a < 2; a++)
#pragma unroll
        for (int b = 0; b < 5; b++) acc[a][b] = (f32x4){0.f, 0.f, 0.f, 0.f};

    // per-thread staging geometry (constant across steps)
    // A: r=0..3, flat = tid + r*512: m = flat>>4, kk = (flat&15)*2
    // B: r=0..1, flat = tid + r*512 (<640): n = flat>>2, seg = flat&3
    float2 aReg[4];
    uint4 bRegH[2], bRegL[2];

    auto loadA = [&](int k0) {
#pragma unroll
        for (int r = 0; r < 4; r++) {
            int flat = tid + r * 512;
            int m = flat >> 4, kk = (flat & 15) * 2;
            int gk = k0 + kk;
            float2 v = make_float2(0.f, 0.f);
            if (gk + 1 < 8150) v = *(const float2*)&X[(size_t)(bm + m) * 8150 + gk];
            aReg[r] = v;
        }
    };
    auto loadB = [&](int k0) {
#pragma unroll
        for (int r = 0; r < 2; r++) {
            int flat = tid + r * 512;
            if (flat < 640) {
                int n = flat >> 2, seg = flat & 3;
                size_t go = (size_t)(bn + n) * 8192 + k0 + seg * 8;
                bRegH[r] = *(const uint4*)&Et_hi[go];
                bRegL[r] = *(const uint4*)&Et_lo[go];
            }
        }
    };
    auto writeAB = [&]() {
#pragma unroll
        for (int r = 0; r < 4; r++) {
            int flat = tid + r * 512;
            int m = flat >> 4, kk = (flat & 15) * 2;
            float vx = aReg[r].x, vy = aReg[r].y;
            ushort hx = f2bf(vx), hy = f2bf(vy);
            ushort2 h; h.x = hx; h.y = hy;
            ushort2 l; l.x = f2bf(vx - bf2f(hx)); l.y = f2bf(vy - bf2f(hy));
            *(ushort2*)&Ah[m * LSTRIDE + kk] = h;
            *(ushort2*)&Al[m * LSTRIDE + kk] = l;
        }
#pragma unroll
        for (int r = 0; r < 2; r++) {
            int flat = tid + r * 512;
            if (flat < 640) {
                int n = flat >> 2, seg = flat & 3;
                *(uint4*)&Bh[n * LSTRIDE + seg * 8] = bRegH[r];
                *(uint4*)&Bl[n * LSTRIDE + seg * 8] = bRegL[r];
            }
        }
    };

    // prologue: stage step 0
    loadA(kc);
    loadB(kc);
    writeAB();
    asm volatile("s_waitcnt lgkmcnt(0)" ::: "memory");
    __builtin_amdgcn_s_barrier();

    for (int step = 0; step < 16; step++) {
        // issue next tile's global loads (stay in flight through MFMA phase)
        if (step < 15) {
            int k0n = kc + (step + 1) * 32;
            loadA(k0n);
            loadB(k0n);
        }
        // compute on current LDS tile
        bf16x8 a_h[2], a_l[2];
#pragma unroll
        for (int mf = 0; mf < 2; mf++) {
            int row = wm + mf * 16 + l16;
            a_h[mf] = *(const bf16x8*)&Ah[row * LSTRIDE + quad * 8];
            a_l[mf] = *(const bf16x8*)&Al[row * LSTRIDE + quad * 8];
        }
#pragma unroll
        for (int nf = 0; nf < 5; nf++) {
            int col = wn + nf * 16 + l16;
            bf16x8 b_h = *(const bf16x8*)&Bh[col * LSTRIDE + quad * 8];
            bf16x8 b_l = *(const bf16x8*)&Bl[col * LSTRIDE + quad * 8];
#pragma unroll
            for (int mf = 0; mf < 2; mf++) {
                acc[mf][nf] = __builtin_amdgcn_mfma_f32_16x16x32_bf16(a_h[mf], b_h, acc[mf][nf], 0, 0, 0);
                acc[mf][nf] = __builtin_amdgcn_mfma_f32_16x16x32_bf16(a_h[mf], b_l, acc[mf][nf], 0, 0, 0);
                acc[mf][nf] = __builtin_amdgcn_mfma_f32_16x16x32_bf16(a_l[mf], b_h, acc[mf][nf], 0, 0, 0);
            }
        }
        asm volatile("s_waitcnt lgkmcnt(0)" ::: "memory");
        __builtin_amdgcn_s_barrier();          // all reads of tile t done
        if (step < 15) {
            writeAB();                          // vmcnt waits inserted at use
            asm volatile("s_waitcnt lgkmcnt(0)" ::: "memory");
        }
        __builtin_amdgcn_s_barrier();          // tile t+1 visible
    }

#pragma unroll
    for (int mf = 0; mf < 2; mf++)
#pragma unroll
        for (int nf = 0; nf < 5; nf++) {
            int row = bm + wm + mf * 16 + quad * 4;
            int col = bn + wn + nf * 16 + l16;
#pragma unroll
            for (int i = 0; i < 4; i++)
                atomicAdd(&Eo[(size_t)(row + i) * 320 + col], acc[mf][nf][i]);
        }
}

// ---------------------------------------------------------------------------
// Stage 2 (small GEMM): Zx[5888][512] = Eo[5888][320] @ W[0:300][512].
// ---------------------------------------------------------------------------
__global__ __launch_bounds__(512, 4) void ze_kernel(
    const float* __restrict__ Eo, const float* __restrict__ W,
    float* __restrict__ Zx) {
    __shared__ ushort Ah[128 * LSTRIDE], Al[128 * LSTRIDE];
    __shared__ ushort Bh[128 * LSTRIDE], Bl[128 * LSTRIDE];
    int bm = blockIdx.x * 128;
    int bn = blockIdx.y * 128;
    int tid = threadIdx.x;
    int lane = tid & 63, w = tid >> 6;
    int quad = lane >> 4, l16 = lane & 15;
    int wm = (w & 3) * 32, wn = (w >> 2) * 64;

    f32x4 acc[2][4];
#pragma unroll
    for (int a = 0; a < 2; a++)
#pragma unroll
        for (int b = 0; b < 4; b++) acc[a][b] = (f32x4){0.f, 0.f, 0.f, 0.f};

    for (int k0 = 0; k0 < 320; k0 += 32) {
        // A staging: Eo[bm+m][k0..k0+31] -> hi/lo bf16 (always in-bounds)
#pragma unroll
        for (int r = 0; r < 2; r++) {
            int flat = tid + r * 512;              // 0..1023
            int m = flat >> 3, kk4 = (flat & 7) * 4;
            float4 v = *(const float4*)&Eo[(size_t)(bm + m) * 320 + k0 + kk4];
            ushort4 h, l;
            h.x = f2bf(v.x); l.x = f2bf(v.x - bf2f(h.x));
            h.y = f2bf(v.y); l.y = f2bf(v.y - bf2f(h.y));
            h.z = f2bf(v.z); l.z = f2bf(v.z - bf2f(h.z));
            h.w = f2bf(v.w); l.w = f2bf(v.w - bf2f(h.w));
            *(ushort4*)&Ah[m * LSTRIDE + kk4] = h;
            *(ushort4*)&Al[m * LSTRIDE + kk4] = l;
        }
        // B staging: W[k][bn+n] -> transposed LDS Bt[n][k] hi/lo (guard k<300)
#pragma unroll
        for (int p = 0; p < 8; p++) {
            int kk = (tid >> 7) + p * 4;           // 0..31
            int n = tid & 127;
            int gk = k0 + kk;
            float v = (gk < 300) ? W[(size_t)gk * 512 + bn + n] : 0.f;
            ushort h = f2bf(v);
            Bh[n * LSTRIDE + kk] = h;
            Bl[n * LSTRIDE + kk] = f2bf(v - bf2f(h));
        }
        __syncthreads();
        bf16x8 a_h[2], a_l[2];
#pragma unroll
        for (int mf = 0; mf < 2; mf++) {
            int row = wm + mf * 16 + l16;
            a_h[mf] = *(const bf16x8*)&Ah[row * LSTRIDE + quad * 8];
            a_l[mf] = *(const bf16x8*)&Al[row * LSTRIDE + quad * 8];
        }
#pragma unroll
        for (int nf = 0; nf < 4; nf++) {
            int col = wn + nf * 16 + l16;
            bf16x8 b_h = *(const bf16x8*)&Bh[col * LSTRIDE + quad * 8];
            bf16x8 b_l = *(const bf16x8*)&Bl[col * LSTRIDE + quad * 8];
#pragma unroll
            for (int mf = 0; mf < 2; mf++) {
                acc[mf][nf] = __builtin_amdgcn_mfma_f32_16x16x32_bf16(a_h[mf], b_h, acc[mf][nf], 0, 0, 0);
                acc[mf][nf] = __builtin_amdgcn_mfma_f32_16x16x32_bf16(a_h[mf], b_l, acc[mf][nf], 0, 0, 0);
                acc[mf][nf] = __builtin_amdgcn_mfma_f32_16x16x32_bf16(a_l[mf], b_h, acc[mf][nf], 0, 0, 0);
            }
        }
        __syncthreads();
    }
#pragma unroll
    for (int mf = 0; mf < 2; mf++)
#pragma unroll
        for (int nf = 0; nf < 4; nf++) {
            int row = bm + wm + mf * 16 + quad * 4;
            int col = bn + wn + nf * 16 + l16;
#pragma unroll
            for (int i = 0; i < 4; i++)
                Zx[(size_t)(row + i) * 512 + col] = acc[mf][nf][i];
        }
}

#define TT 46

__device__ __forceinline__ float sigf(float x) { return 1.f / (1.f + expf(-x)); }

// LayerNorm LSTM recurrence (unchanged from passing baseline).
__global__ __launch_bounds__(256) void lstm_kernel(
    const float* __restrict__ Zx1, const float* __restrict__ Zx2,
    const float* __restrict__ W1, const float* __restrict__ W2,
    const float* __restrict__ lng1, const float* __restrict__ lnb1,
    const float* __restrict__ lng2, const float* __restrict__ lnb2,
    float* __restrict__ o1, float* __restrict__ o2) {
    int lstm = blockIdx.x >> 5;
    int r0 = (blockIdx.x & 31) * 4;
    const float* Zx = lstm ? Zx2 : Zx1;
    const float* Wh = (lstm ? W2 : W1) + 300 * 512;
    const float* g  = lstm ? lng2 : lng1;
    const float* bb = lstm ? lnb2 : lnb1;
    float* obuf = lstm ? o2 : o1;

    __shared__ __align__(16) float hs[4][128];
    __shared__ __align__(16) float cs[4][128];
    __shared__ __align__(16) float zb[4][512];
    __shared__ float mu[4][4], rs[4][4], cmu[4], crs[4];

    int tid = threadIdx.x;
    for (int i = tid; i < 512; i += 256) {
        hs[i >> 7][i & 127] = 0.f;
        cs[i >> 7][i & 127] = 0.f;
    }
    __syncthreads();

    for (int t = 0; t < TT; t++) {
        int c0 = tid * 2;
        float2 acc[4];
#pragma unroll
        for (int r = 0; r < 4; r++)
            acc[r] = *(const float2*)&Zx[((size_t)(r0 + r) * TT + t) * 512 + c0];
        for (int k = 0; k < 128; k += 4) {
            float4 h4[4];
#pragma unroll
            for (int r = 0; r < 4; r++) h4[r] = *(const float4*)&hs[r][k];
#pragma unroll
            for (int kk = 0; kk < 4; kk++) {
                float2 wv = *(const float2*)&Wh[(size_t)(k + kk) * 512 + c0];
#pragma unroll
                for (int r = 0; r < 4; r++) {
                    float hk = ((const float*)&h4[r])[kk];
                    acc[r].x = fmaf(hk, wv.x, acc[r].x);
                    acc[r].y = fmaf(hk, wv.y, acc[r].y);
                }
            }
        }
#pragma unroll
        for (int r = 0; r < 4; r++) {
            zb[r][c0] = acc[r].x;
            zb[r][c0 + 1] = acc[r].y;
        }
        __syncthreads();

        {
            int grp = tid >> 4;
            int row = grp >> 2, gate = grp & 3;
            int l = tid & 15;
            float s = 0.f, ss = 0.f;
#pragma unroll
            for (int j = 0; j < 8; j++) {
                float v = zb[row][gate * 128 + l + j * 16];
                s += v; ss += v * v;
            }
#pragma unroll
            for (int off = 1; off < 16; off <<= 1) {
                s += __shfl_xor(s, off);
                ss += __shfl_xor(ss, off);
            }
            if (l == 0) {
                float m_ = s * (1.f / 128.f);
                mu[row][gate] = m_;
                rs[row][gate] = rsqrtf(ss * (1.f / 128.f) - m_ * m_ + 1e-12f);
            }
        }
        __syncthreads();

        float ogate[2];
#pragma unroll
        for (int ii = 0; ii < 2; ii++) {
            int idx = tid + ii * 256;
            int row = idx >> 7, col = idx & 127;
            float i_g = (zb[row][col]       - mu[row][0]) * rs[row][0] * g[0 * 128 + col] + bb[0 * 128 + col];
            float j_g = (zb[row][128 + col] - mu[row][1]) * rs[row][1] * g[1 * 128 + col] + bb[1 * 128 + col];
            float f_g = (zb[row][256 + col] - mu[row][2]) * rs[row][2] * g[2 * 128 + col] + bb[2 * 128 + col];
            float o_g = (zb[row][384 + col] - mu[row][3]) * rs[row][3] * g[3 * 128 + col] + bb[3 * 128 + col];
            float nc = cs[row][col] * sigf(f_g + 1.f) + sigf(i_g) * fmaxf(j_g, 0.f);
            cs[row][col] = nc;
            ogate[ii] = o_g;
        }
        __syncthreads();

        {
            int ww = tid >> 6, l = tid & 63;
            float v0 = cs[ww][l], v1 = cs[ww][l + 64];
            float s = v0 + v1, ss = v0 * v0 + v1 * v1;
#pragma unroll
            for (int off = 1; off < 64; off <<= 1) {
                s += __shfl_xor(s, off);
                ss += __shfl_xor(ss, off);
            }
            if (l == 0) {
                float m_ = s * (1.f / 128.f);
                cmu[ww] = m_;
                crs[ww] = rsqrtf(ss * (1.f / 128.f) - m_ * m_ + 1e-12f);
            }
        }
        __syncthreads();

#pragma unroll
        for (int ii = 0; ii < 2; ii++) {
            int idx = tid + ii * 256;
            int row = idx >> 7, col = idx & 127;
            float lnc = (cs[row][col] - cmu[row]) * crs[row] * g[4 * 128 + col] + bb[4 * 128 + col];
            float hv = fmaxf(lnc, 0.f) * sigf(ogate[ii]);
            hs[row][col] = hv;
            obuf[((size_t)(r0 + row) * TT + t) * 128 + col] = hv;
        }
        __syncthreads();
    }
}

// Attention (unchanged).
__global__ __launch_bounds__(256) void attn_kernel(
    const float* __restrict__ o1, const float* __restrict__ o2,
    const float* __restrict__ v1, const float* __restrict__ v2,
    const float* __restrict__ Wo1, const float* __restrict__ Wo2,
    const float* __restrict__ bo1, const float* __restrict__ bo2,
    float* __restrict__ acat) {
    int lstm = blockIdx.x >> 7;
    int b = blockIdx.x & 127;
    const float* o  = (lstm ? o2 : o1) + (size_t)b * TT * 128;
    const float* v  = lstm ? v2 : v1;
    const float* Wo = lstm ? Wo2 : Wo1;
    const float* bo = lstm ? bo2 : bo1;
    __shared__ float sc[64];
    __shared__ float ctx[128];
    int tid = threadIdx.x;
    if (tid < TT) {
        float s = 0.f;
        for (int h = 0; h < 128; h++) s = fmaf(o[tid * 128 + h], v[h], s);
        sc[tid] = s;
    }
    __syncthreads();
    if (tid < 64) {
        float x = (tid < TT) ? sc[tid] : -1e30f;
        float m = x;
#pragma unroll
        for (int off = 1; off < 64; off <<= 1) m = fmaxf(m, __shfl_xor(m, off));
        float e = (tid < TT) ? expf(x - m) : 0.f;
        float s = e;
#pragma unroll
        for (int off = 1; off < 64; off <<= 1) s += __shfl_xor(s, off);
        if (tid < TT) sc[tid] = e / s;
    }
    __syncthreads();
    if (tid < 128) {
        float s = 0.f;
        for (int t = 0; t < TT; t++) s = fmaf(sc[t], o[t * 128 + tid], s);
        ctx[tid] = s;
    }
    __syncthreads();
#pragma unroll
    for (int j = 0; j < 2; j++) {
        int n = tid * 2 + j;
        float s = bo[n];
        for (int h = 0; h < 128; h++) s = fmaf(ctx[h], Wo[h * 512 + n], s);
        acat[(size_t)b * 1024 + lstm * 512 + n] = fmaxf(s, 0.f);
    }
}

// Final MLP (unchanged).
__global__ __launch_bounds__(256) void final_kernel(
    const float* __restrict__ acat, const float* __restrict__ Wh,
    const float* __restrict__ bh, const float* __restrict__ Wout,
    const float* __restrict__ bout, float* __restrict__ out) {
    int b = blockIdx.x;
    __shared__ float ain[1024];
    __shared__ float hid[512];
    __shared__ float red[4];
    int tid = threadIdx.x;
    for (int i = tid; i < 1024; i += 256) ain[i] = acat[(size_t)b * 1024 + i];
    __syncthreads();
#pragma unroll
    for (int j = 0; j < 2; j++) {
        int n = tid * 2 + j;
        float s = bh[n];
        for (int k = 0; k < 1024; k++) s = fmaf(ain[k], Wh[(size_t)k * 512 + n], s);
        hid[n] = fmaxf(s, 0.f);
    }
    __syncthreads();
    for (int j = 0; j < 2; j++) {
        float p = 0.f;
        for (int k = tid; k < 512; k += 256) p = fmaf(hid[k], Wout[k * 2 + j], p);
#pragma unroll
        for (int off = 1; off < 64; off <<= 1) p += __shfl_xor(p, off);
        if ((tid & 63) == 0) red[tid >> 6] = p;
        __syncthreads();
        if (tid == 0) out[b * 2 + j] = red[0] + red[1] + red[2] + red[3] + bout[j];
        __syncthreads();
    }
}

extern "C" void kernel_launch(void* const* d_in, const int* in_sizes, int n_in,
                              void* d_out, int out_size, void* d_ws, size_t ws_size,
                              hipStream_t stream) {
    const float* x1      = (const float*)d_in[0];
    const float* x2      = (const float*)d_in[1];
    const float* embed1  = (const float*)d_in[2];
    const float* embed2  = (const float*)d_in[3];
    const float* W_lstm1 = (const float*)d_in[4];
    const float* W_lstm2 = (const float*)d_in[5];
    const float* lng1    = (const float*)d_in[6];
    const float* lnb1    = (const float*)d_in[7];
    const float* lng2    = (const float*)d_in[8];
    const float* lnb2    = (const float*)d_in[9];
    const float* attn_v1 = (const float*)d_in[10];
    const float* attn_Wo1= (const float*)d_in[11];
    const float* attn_bo1= (const float*)d_in[12];
    const float* attn_v2 = (const float*)d_in[13];
    const float* attn_Wo2= (const float*)d_in[14];
    const float* attn_bo2= (const float*)d_in[15];
    const float* W_h     = (const float*)d_in[16];
    const float* b_h     = (const float*)d_in[17];
    const float* W_out   = (const float*)d_in[18];
    const float* b_out   = (const float*)d_in[19];
    float* out = (float*)d_out;

    // Workspace layout (~46.4 MB)
    ushort* Et_hi = (ushort*)d_ws;                       // 320*8192 bf16
    ushort* Et_lo = Et_hi + (size_t)320 * 8192;          // 320*8192 bf16
    float* Eo  = (float*)(Et_lo + (size_t)320 * 8192);   // 5888*320 f32
    float* Zx1 = Eo + (size_t)5888 * 320;                // 5888*512 f32
    float* Zx2 = Zx1 + 3014656;
    float* o1  = Zx2 + 3014656;                          // 128*46*128
    float* o2  = o1 + 753664;
    float* acat = o2 + 753664;                           // 128*1024

    // Branch 1: transpose embed -> big GEMM (X@embed) -> small GEMM (@W)
    hipMemsetAsync(Eo, 0, (size_t)5888 * 320 * 4, stream);
    trans_kernel<<<dim3(128, 5), 256, 0, stream>>>(embed1, Et_hi, Et_lo);
    e_kernel<<<dim3(46, 2, 16), 512, 0, stream>>>(x1, Et_hi, Et_lo, Eo);
    ze_kernel<<<dim3(46, 4), 512, 0, stream>>>(Eo, W_lstm1, Zx1);
    // Branch 2 (reuses Et/Eo buffers; stream-ordered)
    hipMemsetAsync(Eo, 0, (size_t)5888 * 320 * 4, stream);
    trans_kernel<<<dim3(128, 5), 256, 0, stream>>>(embed2, Et_hi, Et_lo);
    e_kernel<<<dim3(46, 2, 16), 512, 0, stream>>>(x2, Et_hi, Et_lo, Eo);
    ze_kernel<<<dim3(46, 4), 512, 0, stream>>>(Eo, W_lstm2, Zx2);

    lstm_kernel<<<64, 256, 0, stream>>>(Zx1, Zx2, W_lstm1, W_lstm2,
                                        lng1, lnb1, lng2, lnb2, o1, o2);
    attn_kernel<<<256, 256, 0, stream>>>(o1, o2, attn_v1, attn_v2,
                                         attn_Wo1, attn_Wo2, attn_bo1, attn_bo2, acat);
    final_kernel<<<128, 256, 0, stream>>>(acat, W_h, b_h, W_out, b_out, out);
}

// Round 3
// 1131.530 us; speedup vs baseline: 1.2389x; 1.2389x over previous
//
#include <hip/hip_runtime.h>
#include <math.h>

typedef short bf16x8 __attribute__((ext_vector_type(8)));
typedef float f32x4 __attribute__((ext_vector_type(4)));

__device__ __forceinline__ ushort f2bf(float f) {
    unsigned u = __float_as_uint(f);
    u = u + 0x7FFFu + ((u >> 16) & 1u);
    return (ushort)(u >> 16);
}
__device__ __forceinline__ float bf2f(ushort h) {
    return __uint_as_float(((unsigned)h) << 16);
}

#define LSTRIDE 40   // LDS row stride in bf16 elements (32 data + 8 pad, 80B rows)

// ---------------------------------------------------------------------------
// Stage 0: transpose embed[8150,300] -> Et[320][8192] bf16 hi/lo (pad = 0).
// ---------------------------------------------------------------------------
__global__ __launch_bounds__(256) void trans_kernel(
    const float* __restrict__ embed, ushort* __restrict__ Et_hi,
    ushort* __restrict__ Et_lo) {
    __shared__ float tile[64][65];
    int k0 = blockIdx.x * 64;
    int n0 = blockIdx.y * 64;
    int tid = threadIdx.x;
#pragma unroll
    for (int i = 0; i < 16; i++) {
        int idx = tid + i * 256;
        int r = idx >> 6, c = idx & 63;
        int gk = k0 + r, gn = n0 + c;
        float v = (gk < 8150 && gn < 300) ? embed[(size_t)gk * 300 + gn] : 0.f;
        tile[r][c] = v;
    }
    __syncthreads();
#pragma unroll
    for (int i = 0; i < 16; i++) {
        int idx = tid + i * 256;
        int n = idx >> 6, k = idx & 63;
        float v = tile[k][n];
        ushort h = f2bf(v);
        Et_hi[(size_t)(n0 + n) * 8192 + k0 + k] = h;
        Et_lo[(size_t)(n0 + n) * 8192 + k0 + k] = f2bf(v - bf2f(h));
    }
}

// ---------------------------------------------------------------------------
// Stage 1 (dominant GEMM): Eo[5888][320] += X[5888][8150] @ embed (via Et).
// T14 async-STAGE pipeline with NAMED registers (no arrays/lambdas -> no
// scratch). Issue t+1 global loads before MFMA of t; vmcnt waits are
// compiler-inserted at first use in the write phase after the barrier.
// grid (46 m-blocks of 128, 2 n-cols of 160, 16 k-chunks of 512), 512 thr.
// ---------------------------------------------------------------------------
__global__ __launch_bounds__(512, 4) void e_kernel(
    const float* __restrict__ X, const ushort* __restrict__ Et_hi,
    const ushort* __restrict__ Et_lo, float* __restrict__ Eo) {
    __shared__ ushort Ah[128 * LSTRIDE], Al[128 * LSTRIDE];
    __shared__ ushort Bh[160 * LSTRIDE], Bl[160 * LSTRIDE];
    int bm = blockIdx.x * 128;
    int bn = blockIdx.y * 160;
    int kc = blockIdx.z * 512;
    int tid = threadIdx.x;
    int lane = tid & 63, w = tid >> 6;
    int quad = lane >> 4, l16 = lane & 15;
    int wm = (w & 3) * 32, wn = (w >> 2) * 80;

    // A staging geometry: r=0..3: flat=tid+512r -> m = (tid>>4)+32r, kk=(tid&15)*2
    int mA0 = tid >> 4, kA0 = (tid & 15) * 2;
    const float* xb0 = X + (size_t)(bm + mA0) * 8150 + kA0;
    const float* xb1 = xb0 + (size_t)32 * 8150;
    const float* xb2 = xb1 + (size_t)32 * 8150;
    const float* xb3 = xb2 + (size_t)32 * 8150;
    int lA0 = mA0 * LSTRIDE + kA0;            // LDS ushort offsets, +32*LSTRIDE per r
    // B staging geometry: r=0: n=tid>>2 (all threads); r=1: n=128+(tid>>2) (tid<128)
    int nB0 = tid >> 2, segB = tid & 3;
    size_t ebOff = (size_t)(bn + nB0) * 8192 + segB * 8;
    const ushort* ebh0 = Et_hi + ebOff;
    const ushort* ebl0 = Et_lo + ebOff;
    int lB0 = nB0 * LSTRIDE + segB * 8;
    const bool bsec = (tid < 128);
    const bool guard = (kc + 512 > 8150);     // only last k-chunk needs bounds

    f32x4 acc[2][5];
#pragma unroll
    for (int a = 0; a < 2; a++)
#pragma unroll
        for (int b = 0; b < 5; b++) acc[a][b] = (f32x4){0.f, 0.f, 0.f, 0.f};

    float2 a0, a1, a2, a3;
    uint4 bh0, bh1, bl0, bl1;

#define LOADAB(k0)                                                            \
    do {                                                                      \
        if (!guard || ((k0) + kA0 + 1 < 8150)) {                              \
            a0 = *(const float2*)(xb0 + (k0));                                \
            a1 = *(const float2*)(xb1 + (k0));                                \
            a2 = *(const float2*)(xb2 + (k0));                                \
            a3 = *(const float2*)(xb3 + (k0));                                \
        } else {                                                              \
            a0 = make_float2(0.f, 0.f); a1 = a0; a2 = a0; a3 = a0;            \
        }                                                                     \
        bh0 = *(const uint4*)(ebh0 + (k0));                                   \
        bl0 = *(const uint4*)(ebl0 + (k0));                                   \
        if (bsec) {                                                           \
            bh1 = *(const uint4*)(ebh0 + (size_t)128 * 8192 + (k0));          \
            bl1 = *(const uint4*)(ebl0 + (size_t)128 * 8192 + (k0));          \
        }                                                                     \
    } while (0)

#define CVT1(v, H, L)                                                         \
    do { ushort hx = f2bf((v).x), hy = f2bf((v).y);                           \
         (H).x = hx; (H).y = hy;                                              \
         (L).x = f2bf((v).x - bf2f(hx)); (L).y = f2bf((v).y - bf2f(hy)); } while (0)

#define WRITEAB()                                                             \
    do {                                                                      \
        ushort2 h0, l0, h1, l1, h2, l2, h3, l3;                               \
        CVT1(a0, h0, l0); CVT1(a1, h1, l1); CVT1(a2, h2, l2); CVT1(a3, h3, l3);\
        *(ushort2*)&Ah[lA0] = h0;                 *(ushort2*)&Al[lA0] = l0;   \
        *(ushort2*)&Ah[lA0 + 32 * LSTRIDE] = h1;  *(ushort2*)&Al[lA0 + 32 * LSTRIDE] = l1; \
        *(ushort2*)&Ah[lA0 + 64 * LSTRIDE] = h2;  *(ushort2*)&Al[lA0 + 64 * LSTRIDE] = l2; \
        *(ushort2*)&Ah[lA0 + 96 * LSTRIDE] = h3;  *(ushort2*)&Al[lA0 + 96 * LSTRIDE] = l3; \
        *(uint4*)&Bh[lB0] = bh0; *(uint4*)&Bl[lB0] = bl0;                     \
        if (bsec) {                                                           \
            *(uint4*)&Bh[lB0 + 128 * LSTRIDE] = bh1;                          \
            *(uint4*)&Bl[lB0 + 128 * LSTRIDE] = bl1;                          \
        }                                                                     \
    } while (0)

    // prologue: stage step 0
    LOADAB(kc);
    WRITEAB();
    asm volatile("s_waitcnt lgkmcnt(0)" ::: "memory");
    __builtin_amdgcn_s_barrier();

    for (int step = 0; step < 16; step++) {
        // issue next tile's global loads (stay in flight through MFMA phase)
        if (step < 15) {
            int k0n = kc + (step + 1) * 32;
            LOADAB(k0n);
        }
        // compute on current LDS tile
        bf16x8 a_h[2], a_l[2];
#pragma unroll
        for (int mf = 0; mf < 2; mf++) {
            int row = wm + mf * 16 + l16;
            a_h[mf] = *(const bf16x8*)&Ah[row * LSTRIDE + quad * 8];
            a_l[mf] = *(const bf16x8*)&Al[row * LSTRIDE + quad * 8];
        }
        __builtin_amdgcn_s_setprio(1);
#pragma unroll
        for (int nf = 0; nf < 5; nf++) {
            int col = wn + nf * 16 + l16;
            bf16x8 b_h = *(const bf16x8*)&Bh[col * LSTRIDE + quad * 8];
            bf16x8 b_l = *(const bf16x8*)&Bl[col * LSTRIDE + quad * 8];
#pragma unroll
            for (int mf = 0; mf < 2; mf++) {
                acc[mf][nf] = __builtin_amdgcn_mfma_f32_16x16x32_bf16(a_h[mf], b_h, acc[mf][nf], 0, 0, 0);
                acc[mf][nf] = __builtin_amdgcn_mfma_f32_16x16x32_bf16(a_h[mf], b_l, acc[mf][nf], 0, 0, 0);
                acc[mf][nf] = __builtin_amdgcn_mfma_f32_16x16x32_bf16(a_l[mf], b_h, acc[mf][nf], 0, 0, 0);
            }
        }
        __builtin_amdgcn_s_setprio(0);
        asm volatile("s_waitcnt lgkmcnt(0)" ::: "memory");
        __builtin_amdgcn_s_barrier();          // all reads of tile t done
        if (step < 15) {
            WRITEAB();                          // vmcnt waits inserted at use
            asm volatile("s_waitcnt lgkmcnt(0)" ::: "memory");
        }
        __builtin_amdgcn_s_barrier();          // tile t+1 visible
    }
#undef LOADAB
#undef CVT1
#undef WRITEAB

#pragma unroll
    for (int mf = 0; mf < 2; mf++)
#pragma unroll
        for (int nf = 0; nf < 5; nf++) {
            int row = bm + wm + mf * 16 + quad * 4;
            int col = bn + wn + nf * 16 + l16;
#pragma unroll
            for (int i = 0; i < 4; i++)
                atomicAdd(&Eo[(size_t)(row + i) * 320 + col], acc[mf][nf][i]);
        }
}

// ---------------------------------------------------------------------------
// Stage 2 (small GEMM): Zx[5888][512] = Eo[5888][320] @ W[0:300][512].
// ---------------------------------------------------------------------------
__global__ __launch_bounds__(512, 4) void ze_kernel(
    const float* __restrict__ Eo, const float* __restrict__ W,
    float* __restrict__ Zx) {
    __shared__ ushort Ah[128 * LSTRIDE], Al[128 * LSTRIDE];
    __shared__ ushort Bh[128 * LSTRIDE], Bl[128 * LSTRIDE];
    int bm = blockIdx.x * 128;
    int bn = blockIdx.y * 128;
    int tid = threadIdx.x;
    int lane = tid & 63, w = tid >> 6;
    int quad = lane >> 4, l16 = lane & 15;
    int wm = (w & 3) * 32, wn = (w >> 2) * 64;

    f32x4 acc[2][4];
#pragma unroll
    for (int a = 0; a < 2; a++)
#pragma unroll
        for (int b = 0; b < 4; b++) acc[a][b] = (f32x4){0.f, 0.f, 0.f, 0.f};

    for (int k0 = 0; k0 < 320; k0 += 32) {
        // A staging: Eo[bm+m][k0..k0+31] -> hi/lo bf16 (always in-bounds)
#pragma unroll
        for (int r = 0; r < 2; r++) {
            int flat = tid + r * 512;              // 0..1023
            int m = flat >> 3, kk4 = (flat & 7) * 4;
            float4 v = *(const float4*)&Eo[(size_t)(bm + m) * 320 + k0 + kk4];
            ushort4 h, l;
            h.x = f2bf(v.x); l.x = f2bf(v.x - bf2f(h.x));
            h.y = f2bf(v.y); l.y = f2bf(v.y - bf2f(h.y));
            h.z = f2bf(v.z); l.z = f2bf(v.z - bf2f(h.z));
            h.w = f2bf(v.w); l.w = f2bf(v.w - bf2f(h.w));
            *(ushort4*)&Ah[m * LSTRIDE + kk4] = h;
            *(ushort4*)&Al[m * LSTRIDE + kk4] = l;
        }
        // B staging: W[k][bn+n] -> transposed LDS Bt[n][k] hi/lo (guard k<300)
#pragma unroll
        for (int p = 0; p < 8; p++) {
            int kk = (tid >> 7) + p * 4;           // 0..31
            int n = tid & 127;
            int gk = k0 + kk;
            float v = (gk < 300) ? W[(size_t)gk * 512 + bn + n] : 0.f;
            ushort h = f2bf(v);
            Bh[n * LSTRIDE + kk] = h;
            Bl[n * LSTRIDE + kk] = f2bf(v - bf2f(h));
        }
        __syncthreads();
        bf16x8 a_h[2], a_l[2];
#pragma unroll
        for (int mf = 0; mf < 2; mf++) {
            int row = wm + mf * 16 + l16;
            a_h[mf] = *(const bf16x8*)&Ah[row * LSTRIDE + quad * 8];
            a_l[mf] = *(const bf16x8*)&Al[row * LSTRIDE + quad * 8];
        }
#pragma unroll
        for (int nf = 0; nf < 4; nf++) {
            int col = wn + nf * 16 + l16;
            bf16x8 b_h = *(const bf16x8*)&Bh[col * LSTRIDE + quad * 8];
            bf16x8 b_l = *(const bf16x8*)&Bl[col * LSTRIDE + quad * 8];
#pragma unroll
            for (int mf = 0; mf < 2; mf++) {
                acc[mf][nf] = __builtin_amdgcn_mfma_f32_16x16x32_bf16(a_h[mf], b_h, acc[mf][nf], 0, 0, 0);
                acc[mf][nf] = __builtin_amdgcn_mfma_f32_16x16x32_bf16(a_h[mf], b_l, acc[mf][nf], 0, 0, 0);
                acc[mf][nf] = __builtin_amdgcn_mfma_f32_16x16x32_bf16(a_l[mf], b_h, acc[mf][nf], 0, 0, 0);
            }
        }
        __syncthreads();
    }
#pragma unroll
    for (int mf = 0; mf < 2; mf++)
#pragma unroll
        for (int nf = 0; nf < 4; nf++) {
            int row = bm + wm + mf * 16 + quad * 4;
            int col = bn + wn + nf * 16 + l16;
#pragma unroll
            for (int i = 0; i < 4; i++)
                Zx[(size_t)(row + i) * 512 + col] = acc[mf][nf][i];
        }
}

#define TT 46

__device__ __forceinline__ float sigf(float x) { return 1.f / (1.f + expf(-x)); }

// LayerNorm LSTM recurrence (unchanged from passing baseline).
__global__ __launch_bounds__(256) void lstm_kernel(
    const float* __restrict__ Zx1, const float* __restrict__ Zx2,
    const float* __restrict__ W1, const float* __restrict__ W2,
    const float* __restrict__ lng1, const float* __restrict__ lnb1,
    const float* __restrict__ lng2, const float* __restrict__ lnb2,
    float* __restrict__ o1, float* __restrict__ o2) {
    int lstm = blockIdx.x >> 5;
    int r0 = (blockIdx.x & 31) * 4;
    const float* Zx = lstm ? Zx2 : Zx1;
    const float* Wh = (lstm ? W2 : W1) + 300 * 512;
    const float* g  = lstm ? lng2 : lng1;
    const float* bb = lstm ? lnb2 : lnb1;
    float* obuf = lstm ? o2 : o1;

    __shared__ __align__(16) float hs[4][128];
    __shared__ __align__(16) float cs[4][128];
    __shared__ __align__(16) float zb[4][512];
    __shared__ float mu[4][4], rs[4][4], cmu[4], crs[4];

    int tid = threadIdx.x;
    for (int i = tid; i < 512; i += 256) {
        hs[i >> 7][i & 127] = 0.f;
        cs[i >> 7][i & 127] = 0.f;
    }
    __syncthreads();

    for (int t = 0; t < TT; t++) {
        int c0 = tid * 2;
        float2 acc[4];
#pragma unroll
        for (int r = 0; r < 4; r++)
            acc[r] = *(const float2*)&Zx[((size_t)(r0 + r) * TT + t) * 512 + c0];
        for (int k = 0; k < 128; k += 4) {
            float4 h4[4];
#pragma unroll
            for (int r = 0; r < 4; r++) h4[r] = *(const float4*)&hs[r][k];
#pragma unroll
            for (int kk = 0; kk < 4; kk++) {
                float2 wv = *(const float2*)&Wh[(size_t)(k + kk) * 512 + c0];
#pragma unroll
                for (int r = 0; r < 4; r++) {
                    float hk = ((const float*)&h4[r])[kk];
                    acc[r].x = fmaf(hk, wv.x, acc[r].x);
                    acc[r].y = fmaf(hk, wv.y, acc[r].y);
                }
            }
        }
#pragma unroll
        for (int r = 0; r < 4; r++) {
            zb[r][c0] = acc[r].x;
            zb[r][c0 + 1] = acc[r].y;
        }
        __syncthreads();

        {
            int grp = tid >> 4;
            int row = grp >> 2, gate = grp & 3;
            int l = tid & 15;
            float s = 0.f, ss = 0.f;
#pragma unroll
            for (int j = 0; j < 8; j++) {
                float v = zb[row][gate * 128 + l + j * 16];
                s += v; ss += v * v;
            }
#pragma unroll
            for (int off = 1; off < 16; off <<= 1) {
                s += __shfl_xor(s, off);
                ss += __shfl_xor(ss, off);
            }
            if (l == 0) {
                float m_ = s * (1.f / 128.f);
                mu[row][gate] = m_;
                rs[row][gate] = rsqrtf(ss * (1.f / 128.f) - m_ * m_ + 1e-12f);
            }
        }
        __syncthreads();

        float ogate[2];
#pragma unroll
        for (int ii = 0; ii < 2; ii++) {
            int idx = tid + ii * 256;
            int row = idx >> 7, col = idx & 127;
            float i_g = (zb[row][col]       - mu[row][0]) * rs[row][0] * g[0 * 128 + col] + bb[0 * 128 + col];
            float j_g = (zb[row][128 + col] - mu[row][1]) * rs[row][1] * g[1 * 128 + col] + bb[1 * 128 + col];
            float f_g = (zb[row][256 + col] - mu[row][2]) * rs[row][2] * g[2 * 128 + col] + bb[2 * 128 + col];
            float o_g = (zb[row][384 + col] - mu[row][3]) * rs[row][3] * g[3 * 128 + col] + bb[3 * 128 + col];
            float nc = cs[row][col] * sigf(f_g + 1.f) + sigf(i_g) * fmaxf(j_g, 0.f);
            cs[row][col] = nc;
            ogate[ii] = o_g;
        }
        __syncthreads();

        {
            int ww = tid >> 6, l = tid & 63;
            float v0 = cs[ww][l], v1 = cs[ww][l + 64];
            float s = v0 + v1, ss = v0 * v0 + v1 * v1;
#pragma unroll
            for (int off = 1; off < 64; off <<= 1) {
                s += __shfl_xor(s, off);
                ss += __shfl_xor(ss, off);
            }
            if (l == 0) {
                float m_ = s * (1.f / 128.f);
                cmu[ww] = m_;
                crs[ww] = rsqrtf(ss * (1.f / 128.f) - m_ * m_ + 1e-12f);
            }
        }
        __syncthreads();

#pragma unroll
        for (int ii = 0; ii < 2; ii++) {
            int idx = tid + ii * 256;
            int row = idx >> 7, col = idx & 127;
            float lnc = (cs[row][col] - cmu[row]) * crs[row] * g[4 * 128 + col] + bb[4 * 128 + col];
            float hv = fmaxf(lnc, 0.f) * sigf(ogate[ii]);
            hs[row][col] = hv;
            obuf[((size_t)(r0 + row) * TT + t) * 128 + col] = hv;
        }
        __syncthreads();
    }
}

// Attention (unchanged).
__global__ __launch_bounds__(256) void attn_kernel(
    const float* __restrict__ o1, const float* __restrict__ o2,
    const float* __restrict__ v1, const float* __restrict__ v2,
    const float* __restrict__ Wo1, const float* __restrict__ Wo2,
    const float* __restrict__ bo1, const float* __restrict__ bo2,
    float* __restrict__ acat) {
    int lstm = blockIdx.x >> 7;
    int b = blockIdx.x & 127;
    const float* o  = (lstm ? o2 : o1) + (size_t)b * TT * 128;
    const float* v  = lstm ? v2 : v1;
    const float* Wo = lstm ? Wo2 : Wo1;
    const float* bo = lstm ? bo2 : bo1;
    __shared__ float sc[64];
    __shared__ float ctx[128];
    int tid = threadIdx.x;
    if (tid < TT) {
        float s = 0.f;
        for (int h = 0; h < 128; h++) s = fmaf(o[tid * 128 + h], v[h], s);
        sc[tid] = s;
    }
    __syncthreads();
    if (tid < 64) {
        float x = (tid < TT) ? sc[tid] : -1e30f;
        float m = x;
#pragma unroll
        for (int off = 1; off < 64; off <<= 1) m = fmaxf(m, __shfl_xor(m, off));
        float e = (tid < TT) ? expf(x - m) : 0.f;
        float s = e;
#pragma unroll
        for (int off = 1; off < 64; off <<= 1) s += __shfl_xor(s, off);
        if (tid < TT) sc[tid] = e / s;
    }
    __syncthreads();
    if (tid < 128) {
        float s = 0.f;
        for (int t = 0; t < TT; t++) s = fmaf(sc[t], o[t * 128 + tid], s);
        ctx[tid] = s;
    }
    __syncthreads();
#pragma unroll
    for (int j = 0; j < 2; j++) {
        int n = tid * 2 + j;
        float s = bo[n];
        for (int h = 0; h < 128; h++) s = fmaf(ctx[h], Wo[h * 512 + n], s);
        acat[(size_t)b * 1024 + lstm * 512 + n] = fmaxf(s, 0.f);
    }
}

// Final MLP (unchanged).
__global__ __launch_bounds__(256) void final_kernel(
    const float* __restrict__ acat, const float* __restrict__ Wh,
    const float* __restrict__ bh, const float* __restrict__ Wout,
    const float* __restrict__ bout, float* __restrict__ out) {
    int b = blockIdx.x;
    __shared__ float ain[1024];
    __shared__ float hid[512];
    __shared__ float red[4];
    int tid = threadIdx.x;
    for (int i = tid; i < 1024; i += 256) ain[i] = acat[(size_t)b * 1024 + i];
    __syncthreads();
#pragma unroll
    for (int j = 0; j < 2; j++) {
        int n = tid * 2 + j;
        float s = bh[n];
        for (int k = 0; k < 1024; k++) s = fmaf(ain[k], Wh[(size_t)k * 512 + n], s);
        hid[n] = fmaxf(s, 0.f);
    }
    __syncthreads();
    for (int j = 0; j < 2; j++) {
        float p = 0.f;
        for (int k = tid; k < 512; k += 256) p = fmaf(hid[k], Wout[k * 2 + j], p);
#pragma unroll
        for (int off = 1; off < 64; off <<= 1) p += __shfl_xor(p, off);
        if ((tid & 63) == 0) red[tid >> 6] = p;
        __syncthreads();
        if (tid == 0) out[b * 2 + j] = red[0] + red[1] + red[2] + red[3] + bout[j];
        __syncthreads();
    }
}

extern "C" void kernel_launch(void* const* d_in, const int* in_sizes, int n_in,
                              void* d_out, int out_size, void* d_ws, size_t ws_size,
                              hipStream_t stream) {
    const float* x1      = (const float*)d_in[0];
    const float* x2      = (const float*)d_in[1];
    const float* embed1  = (const float*)d_in[2];
    const float* embed2  = (const float*)d_in[3];
    const float* W_lstm1 = (const float*)d_in[4];
    const float* W_lstm2 = (const float*)d_in[5];
    const float* lng1    = (const float*)d_in[6];
    const float* lnb1    = (const float*)d_in[7];
    const float* lng2    = (const float*)d_in[8];
    const float* lnb2    = (const float*)d_in[9];
    const float* attn_v1 = (const float*)d_in[10];
    const float* attn_Wo1= (const float*)d_in[11];
    const float* attn_bo1= (const float*)d_in[12];
    const float* attn_v2 = (const float*)d_in[13];
    const float* attn_Wo2= (const float*)d_in[14];
    const float* attn_bo2= (const float*)d_in[15];
    const float* W_h     = (const float*)d_in[16];
    const float* b_h     = (const float*)d_in[17];
    const float* W_out   = (const float*)d_in[18];
    const float* b_out   = (const float*)d_in[19];
    float* out = (float*)d_out;

    // Workspace layout (~46.4 MB)
    ushort* Et_hi = (ushort*)d_ws;                       // 320*8192 bf16
    ushort* Et_lo = Et_hi + (size_t)320 * 8192;          // 320*8192 bf16
    float* Eo  = (float*)(Et_lo + (size_t)320 * 8192);   // 5888*320 f32
    float* Zx1 = Eo + (size_t)5888 * 320;                // 5888*512 f32
    float* Zx2 = Zx1 + 3014656;
    float* o1  = Zx2 + 3014656;                          // 128*46*128
    float* o2  = o1 + 753664;
    float* acat = o2 + 753664;                           // 128*1024

    // Branch 1: transpose embed -> big GEMM (X@embed) -> small GEMM (@W)
    hipMemsetAsync(Eo, 0, (size_t)5888 * 320 * 4, stream);
    trans_kernel<<<dim3(128, 5), 256, 0, stream>>>(embed1, Et_hi, Et_lo);
    e_kernel<<<dim3(46, 2, 16), 512, 0, stream>>>(x1, Et_hi, Et_lo, Eo);
    ze_kernel<<<dim3(46, 4), 512, 0, stream>>>(Eo, W_lstm1, Zx1);
    // Branch 2 (reuses Et/Eo buffers; stream-ordered)
    hipMemsetAsync(Eo, 0, (size_t)5888 * 320 * 4, stream);
    trans_kernel<<<dim3(128, 5), 256, 0, stream>>>(embed2, Et_hi, Et_lo);
    e_kernel<<<dim3(46, 2, 16), 512, 0, stream>>>(x2, Et_hi, Et_lo, Eo);
    ze_kernel<<<dim3(46, 4), 512, 0, stream>>>(Eo, W_lstm2, Zx2);

    lstm_kernel<<<64, 256, 0, stream>>>(Zx1, Zx2, W_lstm1, W_lstm2,
                                        lng1, lnb1, lng2, lnb2, o1, o2);
    attn_kernel<<<256, 256, 0, stream>>>(o1, o2, attn_v1, attn_v2,
                                         attn_Wo1, attn_Wo2, attn_bo1, attn_bo2, acat);
    final_kernel<<<128, 256, 0, stream>>>(acat, W_h, b_h, W_out, b_out, out);
}